// Round 18
// baseline (71.145 us; speedup 1.0000x reference)
//
#include <hip/hip_runtime.h>
#include <hip/hip_bf16.h>

// TwinPolicy, pure-bf16 MFMA pipeline (5 launches).
// R17: fill shards ride every pre-scatter kernel (keep).
// R18 lever: BARRIER-FREE fragment-direct GEMMs. In a 32x32 tile the A-frag
// is used by exactly ONE wave (LDS staging = pure overhead) and frags are
// contiguous 256B slabs in the packed layout -> load them global->VGPR
// directly. No LDS, no __syncthreads, no vmcnt(0) drains; compiler
// software-pipelines loads across K-steps. Extra A/W re-reads are L2/L3-hot.

typedef unsigned short u16;
typedef unsigned int   u32;
typedef __attribute__((ext_vector_type(8))) short bf16x8;
typedef __attribute__((ext_vector_type(4))) float f32x4;

#define N_NODES 4096
#define E_EDGES 131072
#define AS1 __attribute__((address_space(1)))
#define AS3 __attribute__((address_space(3)))

__device__ __forceinline__ u16 f2bf(float f) {
    u32 u = __float_as_uint(f);
    return (u16)((u + 0x7FFFu + ((u >> 16) & 1u)) >> 16);
}
__device__ __forceinline__ float bflo(u32 w) { return __uint_as_float(w << 16); }
__device__ __forceinline__ float bfhi(u32 w) { return __uint_as_float(w & 0xffff0000u); }

// fill shard s (of 4), block fb (of 128): 128*256*32 float4 = 16.77 MB
__device__ __forceinline__ void fill_shard(float4* __restrict__ out4,
                                           int shard, int fb, int tid)
{
    float4* op = out4 + (size_t)shard * 1048576 + (size_t)fb * 8192 + tid;
    const float4 z = {0.f, 0.f, 0.f, 0.f};
    #pragma unroll 8
    for (int q = 0; q < 32; ++q)
        op[(size_t)q * 256] = z;
}

// ---------------------------------------------------------------------------
// Pack f32 [M][K] -> bf16, MFMA-ready layout:
// elem(row,k) -> ((((row>>6)*KC + (k>>6))*8 + ((k>>3)&7))*64 + (row&63))*8 + (k&7)
// ---------------------------------------------------------------------------
__device__ __forceinline__ void pack_body(const float* __restrict__ in,
                                          u16* __restrict__ hi, int K, int kcs, int gid)
{
    const int r   = gid & 63;
    const int kb  = (gid >> 6) & 7;
    const int pkc = gid >> 9;
    const int kc  = pkc & ((1 << kcs) - 1);
    const int p   = pkc >> kcs;
    const size_t row = ((size_t)p << 6) | r;
    const int k0 = (kc << 6) | (kb << 3);

    const float* src = in + row * (size_t)K + k0;
    const float4 v0 = *(const float4*)src;
    const float4 v1 = *(const float4*)(src + 4);
    const float vv[8] = {v0.x, v0.y, v0.z, v0.w, v1.x, v1.y, v1.z, v1.w};

    u32 hw[4];
    #pragma unroll
    for (int q = 0; q < 4; ++q)
        hw[q] = (u32)f2bf(vv[2 * q]) | ((u32)f2bf(vv[2 * q + 1]) << 16);
    uint4 hv = {hw[0], hw[1], hw[2], hw[3]};
    *(uint4*)(hi + (size_t)gid * 8) = hv;
}

// ---------------------------------------------------------------------------
// prep_all (2242 work + 128 fill = 2370 blocks):
//   [0,2048):     pack ideal (4096x1024) -> xh
//   [2048,2176):  pack W1 (256x1024) -> w1h
//   [2176,2240):  Wab[r][c] = (r<256 ? We1a@W2 : We1b@W2), packed bf16 W-layout
//   [2240,2242):  bab[r] = (r<256 ? be1[r] : 0) + dot(We1 row-part, b2)
//   [2242,2370):  fill shard 0
// ---------------------------------------------------------------------------
__global__ __launch_bounds__(256)
void prep_all(const float* __restrict__ ideal, const float* __restrict__ W1,
              const float* __restrict__ We1, const float* __restrict__ W2,
              const float* __restrict__ b2, const float* __restrict__ be1,
              u16* __restrict__ xh, u16* __restrict__ w1h,
              u16* __restrict__ wabh, float* __restrict__ bab,
              float4* __restrict__ out4)
{
    const int bid = blockIdx.x;
    if (bid < 2048) {
        pack_body(ideal, xh, 1024, 4, bid * 256 + threadIdx.x);
    } else if (bid < 2176) {
        pack_body(W1, w1h, 1024, 4, (bid - 2048) * 256 + threadIdx.x);
    } else if (bid < 2240) {
        const int r0 = (bid - 2176) * 8;
        const int c  = threadIdx.x;
        float acc[8] = {};
        for (int k = 0; k < 256; ++k) {
            const float w2 = W2[k * 256 + c];
            #pragma unroll
            for (int j = 0; j < 8; ++j) {
                const int r = r0 + j;
                acc[j] += We1[(size_t)(r & 255) * 512 + ((r >> 8) << 8) + k] * w2;
            }
        }
        const int kc = c >> 6, kb = (c >> 3) & 7, e = c & 7;
        #pragma unroll
        for (int j = 0; j < 8; ++j) {
            const int r = r0 + j;
            wabh[(((((size_t)(r >> 6) << 2) + kc) << 3) + kb) * 512 + (size_t)(r & 63) * 8 + e]
                = f2bf(acc[j]);
        }
    } else if (bid < 2242) {
        const int r = (bid - 2240) * 256 + threadIdx.x;
        const int i = r & 255;
        const int koff = (r >> 8) << 8;
        float acc = (r < 256) ? be1[i] : 0.0f;
        for (int k = 0; k < 256; k += 4) {
            const float4 w = *(const float4*)(We1 + (size_t)i * 512 + koff + k);
            const float4 b = *(const float4*)(b2 + k);
            acc += w.x * b.x + w.y * b.y + w.z * b.z + w.w * b.w;
        }
        bab[r] = acc;
    } else {
        fill_shard(out4, 0, bid - 2242, threadIdx.x);
    }
}

// ---------------------------------------------------------------------------
// Fragment-direct 32x32 MFMA GEMM: no LDS, no barriers.
// 4 waves (wave = 16x16 quadrant, wr=wv>>1, wc=wv&1); per K-step each lane
// loads its A-frag and B-frag (16B contiguous slabs, coalesced per wave)
// straight from global (L2/L3-hot packed buffers) and issues 2 MFMAs.
// CMODE 0: epilogue relu+bias -> packed A-layout for a K=256 next GEMM.
// CMODE 1: epilogue bias -> bf16 row-major [M][512].
// Blocks with blockIdx.y == NBY are fill blocks (shard SHARD).
// K-order (t asc, s asc, kb=s*4+kq) == R11 exactly (bit-identical).
// ---------------------------------------------------------------------------
template<int KC, int CMODE, int NBY, int SHARD>
__global__ __launch_bounds__(256)
void mfma_gemm32d(const u16* __restrict__ A, const u16* __restrict__ W,
                  const float* __restrict__ bias, u16* __restrict__ Cout,
                  float4* __restrict__ out4)
{
    if (blockIdx.y == NBY) {
        fill_shard(out4, SHARD, blockIdx.x, threadIdx.x);
        return;
    }

    const int tid  = threadIdx.x;
    const int wv   = tid >> 6;
    const int lane = tid & 63;
    const int kq   = lane >> 4;
    const int r16  = lane & 15;
    const int wr   = wv >> 1;
    const int wc   = wv & 1;
    const int bp   = blockIdx.x;              // row-block of 32
    const int bn   = blockIdx.y;              // col-block of 32
    const int p    = bp >> 1, r0 = (bp & 1) << 5;   // source 64-row panel
    const int pn   = bn >> 1, c0 = (bn & 1) << 5;   // source 64-col panel

    // per-lane fragment base pointers (16B slabs, coalesced across r16)
    const u16* pa = A + (((size_t)p * KC) << 12) + ((size_t)(r0 + (wr << 4) + r16) << 3);
    const u16* pw = W + (((size_t)pn * KC) << 12) + ((size_t)(c0 + (wc << 4) + r16) << 3);

    f32x4 acc = (f32x4){0.f, 0.f, 0.f, 0.f};

    #pragma unroll 4
    for (int t = 0; t < KC; ++t) {
        #pragma unroll
        for (int s = 0; s < 2; ++s) {
            const int kb = (s << 2) + kq;
            const bf16x8 af = *(const bf16x8*)(pa + (((size_t)t << 12) + (kb << 9)));
            const bf16x8 bf = *(const bf16x8*)(pw + (((size_t)t << 12) + (kb << 9)));
            acc = __builtin_amdgcn_mfma_f32_16x16x32_bf16(af, bf, acc, 0, 0, 0);
        }
    }

    // C/D: col=lane&15, row=(lane>>4)*4+j within the wave's 16x16 quadrant.
    const int cl = (wc << 4) + r16;           // local col 0..31
    const int C  = (bn << 5) + cl;            // global out col
    const float bv = bias[C];
    if constexpr (CMODE == 0) {
        const int kcn = C >> 6;
        const int kb2 = (C >> 3) & 7;
        const int e2  = C & 7;
        #pragma unroll
        for (int j = 0; j < 4; ++j) {
            const int row = (bp << 5) + (wr << 4) + (kq << 2) + j;
            const float v = fmaxf(acc[j] + bv, 0.0f);
            Cout[((((size_t)(row >> 6) << 2) + kcn) * 8 + kb2) * 512
                 + (size_t)(row & 63) * 8 + e2] = f2bf(v);
        }
    } else {
        #pragma unroll
        for (int j = 0; j < 4; ++j) {
            const int row = (bp << 5) + (wr << 4) + (kq << 2) + j;
            Cout[(size_t)row * 512 + C] = f2bf(acc[j] + bv);
        }
    }
}

// ---------------------------------------------------------------------------
// edge_z (2048 edge + 128 fill = 2176 blocks):
//   blocks [0,2048):    v[e] = exp(score[e]) (no max-sub; |s| = O(1)),
//                       block-partial Z -> part[cb] (only l5==0 lanes add).
//   blocks [2048,2176): fill shard 3
// ---------------------------------------------------------------------------
__global__ __launch_bounds__(256)
void edge_z(const u16* __restrict__ AB, const int* __restrict__ idx,
            const float* __restrict__ We2, const float* __restrict__ be2p,
            float* __restrict__ vbuf, float* __restrict__ part,
            float4* __restrict__ out4)
{
    const int bid = blockIdx.x;
    const int tid = threadIdx.x;

    if (bid >= 2048) {
        fill_shard(out4, 3, bid - 2048, tid);
        return;
    }

    __shared__ float sm[256];
    const int cb   = bid;                        // 0..2047
    const int lane = tid & 63;
    const int sub  = lane >> 5;
    const int l5   = lane & 31;
    const int wid  = (cb * 256 + tid) >> 6;      // 0..8191
    const float be2 = be2p[0];

    float w2v[8];
    #pragma unroll
    for (int q = 0; q < 2; ++q) {
        const float4 w = ((const float4*)We2)[l5 * 2 + q];
        w2v[q * 4 + 0] = w.x; w2v[q * 4 + 1] = w.y;
        w2v[q * 4 + 2] = w.z; w2v[q * 4 + 3] = w.w;
    }

    float zloc = 0.0f;
    #pragma unroll
    for (int it = 0; it < 8; ++it) {
        const int e = (wid << 1) + sub + (it << 14);    // covers [0, 131072)
        const int src = idx[2 * e];
        const int dst = idx[2 * e + 1];
        const uint4 av = *(const uint4*)(AB + ((size_t)src << 9) + (l5 << 3));
        const uint4 bv = *(const uint4*)(AB + ((size_t)dst << 9) + 256 + (l5 << 3));
        const u32 aw[4] = {av.x, av.y, av.z, av.w};
        const u32 bw[4] = {bv.x, bv.y, bv.z, bv.w};
        float p = 0.0f;
        #pragma unroll
        for (int q = 0; q < 4; ++q) {
            p += fmaxf(bflo(aw[q]) + bflo(bw[q]), 0.0f) * w2v[2 * q];
            p += fmaxf(bfhi(aw[q]) + bfhi(bw[q]), 0.0f) * w2v[2 * q + 1];
        }
        #pragma unroll
        for (int m = 16; m > 0; m >>= 1)
            p += __shfl_xor(p, m, 64);   // xor<32: stays within the half-wave
        const float v = expf(p + be2);
        if (l5 == 0) {
            vbuf[e] = v;
            zloc += v;                   // one lane per edge contributes
        }
    }
    sm[tid] = zloc;
    __syncthreads();
    for (int st = 128; st > 0; st >>= 1) {
        if (tid < st) sm[tid] += sm[tid + st];
        __syncthreads();
    }
    if (tid == 0) part[cb] = sm[0];
}

// fused: finalize Z over part[2048] (redundant per block) + scatter probs
__global__ __launch_bounds__(256)
void scatter_probs(const float* __restrict__ vbuf, const int* __restrict__ idx,
                   const float* __restrict__ part, float* __restrict__ out, int n)
{
    __shared__ float sm[256];
    float a = part[threadIdx.x];
    #pragma unroll
    for (int k = 1; k < 8; ++k)
        a += part[threadIdx.x + k * 256];
    sm[threadIdx.x] = a;
    __syncthreads();
    for (int st = 128; st > 0; st >>= 1) {
        if (threadIdx.x < st) sm[threadIdx.x] += sm[threadIdx.x + st];
        __syncthreads();
    }
    const float Z = sm[0];
    const int e = blockIdx.x * 256 + threadIdx.x;
    if (e < n)
        out[(size_t)idx[2 * e] * N_NODES + idx[2 * e + 1]] = vbuf[e] / Z;
}

// ---------------------------------------------------------------------------
extern "C" void kernel_launch(void* const* d_in, const int* in_sizes, int n_in,
                              void* d_out, int out_size, void* d_ws, size_t ws_size,
                              hipStream_t stream)
{
    const float* ideal = (const float*)d_in[0];   // 4096 x 1024
    const int*   idx   = (const int*)d_in[1];     // E x 2
    const float* W1    = (const float*)d_in[2];   // 256 x 1024
    const float* b1    = (const float*)d_in[3];   // 256
    const float* W2    = (const float*)d_in[4];   // 256 x 256
    const float* b2    = (const float*)d_in[5];   // 256
    const float* We1   = (const float*)d_in[6];   // 256 x 512
    const float* be1   = (const float*)d_in[7];   // 256
    const float* We2   = (const float*)d_in[8];   // 256
    const float* be2   = (const float*)d_in[9];   // 1
    float* out = (float*)d_out;

    char* Wb = (char*)d_ws;
    u16*   xh   = (u16*)(Wb);                          // 8 MB packed x
    u16*   w1h  = (u16*)(Wb + (8u << 20));             // 512 KB packed W1
    u16*   wabh = (u16*)(Wb + (8u << 20) + (512u << 10)); // 256 KB packed Wab
    u16*   h1h  = (u16*)(Wb + (9u << 20));             // 2 MB packed h1
    float* bab  = (float*)(Wb + (11u << 20));          // 2 KB
    u16*   ABbf = (u16*)(Wb + (12u << 20));            // 4 MB bf16 AB row-major
    float* vbuf = (float*)(Wb + (16u << 20));          // 512 KB exp(scores)
    float* part = vbuf + E_EDGES;                      // 2048 partial Z

    // pack + fold (+ fill shard 0)
    prep_all<<<2370, 256, 0, stream>>>(ideal, W1, We1, W2, b2, be1,
                                       xh, w1h, wabh, bab, (float4*)out);

    // h1 packed = relu(x @ W1.T + b1)   (1024 work blocks + fill shard 1)
    mfma_gemm32d<16, 0, 8, 1><<<dim3(128, 9), 256, 0, stream>>>(
        xh, w1h, b1, h1h, (float4*)out);
    // AB bf16 = h1 @ Wab.T + bab        (2048 work blocks + fill shard 2)
    mfma_gemm32d<4, 1, 16, 2><<<dim3(128, 17), 256, 0, stream>>>(
        h1h, wabh, bab, ABbf, (float4*)out);

    // edge scores + partial Z (+ fill shard 3)
    edge_z<<<2176, 256, 0, stream>>>(ABbf, idx, We2, be2, vbuf, part, (float4*)out);
    // Z finalize (redundant per block) + scatter
    scatter_probs<<<512, 256, 0, stream>>>(vbuf, idx, part, out, E_EDGES);
}

// Round 19
// 66.671 us; speedup vs baseline: 1.0671x; 1.0671x over previous
//
#include <hip/hip_runtime.h>
#include <hip/hip_bf16.h>

// TwinPolicy, pure-bf16 MFMA pipeline (4 launches):
//   prep_all: pack x -> xh, pack W1 -> w1h, fold Wab -> wabh, bab (+ fill sh0)
//   gemm12: ROW-LOCAL fusion of both GEMMs. Block = 16 rows, 8 waves:
//     phase1 h1=relu(x@W1.T+b1) (K=1024, frags from packed xh/w1h) -> 8KB LDS,
//     ONE __syncthreads, phase2 AB=h1@Wab.T+bab (K=256, Wab frags L2-hot).
//     No per-K-step barriers; kills the h1 global round-trip + one launch.
//     (+ 256 tail blocks fill shards 1,2)
//   edge_z: v[e]=exp(s[e]) + block partial Z (+ fill shard 3)
//   scatter_probs: redundant Z-reduce + out[src,dst] = v/Z
// K-order and f2bf points identical to R17 -> bit-identical output.

typedef unsigned short u16;
typedef unsigned int   u32;
typedef __attribute__((ext_vector_type(8))) short bf16x8;
typedef __attribute__((ext_vector_type(4))) float f32x4;

#define N_NODES 4096
#define E_EDGES 131072
#define AS1 __attribute__((address_space(1)))
#define AS3 __attribute__((address_space(3)))

__device__ __forceinline__ u16 f2bf(float f) {
    u32 u = __float_as_uint(f);
    return (u16)((u + 0x7FFFu + ((u >> 16) & 1u)) >> 16);
}
__device__ __forceinline__ float bflo(u32 w) { return __uint_as_float(w << 16); }
__device__ __forceinline__ float bfhi(u32 w) { return __uint_as_float(w & 0xffff0000u); }

// fill shard s (of 4), block fb (of 128), 256-thr: 128*256*32 float4 = 16.77MB
__device__ __forceinline__ void fill_shard(float4* __restrict__ out4,
                                           int shard, int fb, int tid)
{
    float4* op = out4 + (size_t)shard * 1048576 + (size_t)fb * 8192 + tid;
    const float4 z = {0.f, 0.f, 0.f, 0.f};
    #pragma unroll 8
    for (int q = 0; q < 32; ++q)
        op[(size_t)q * 256] = z;
}

// ---------------------------------------------------------------------------
// Pack f32 [M][K] -> bf16, MFMA-ready layout:
// elem(row,k) -> ((((row>>6)*KC + (k>>6))*8 + ((k>>3)&7))*64 + (row&63))*8 + (k&7)
// ---------------------------------------------------------------------------
__device__ __forceinline__ void pack_body(const float* __restrict__ in,
                                          u16* __restrict__ hi, int K, int kcs, int gid)
{
    const int r   = gid & 63;
    const int kb  = (gid >> 6) & 7;
    const int pkc = gid >> 9;
    const int kc  = pkc & ((1 << kcs) - 1);
    const int p   = pkc >> kcs;
    const size_t row = ((size_t)p << 6) | r;
    const int k0 = (kc << 6) | (kb << 3);

    const float* src = in + row * (size_t)K + k0;
    const float4 v0 = *(const float4*)src;
    const float4 v1 = *(const float4*)(src + 4);
    const float vv[8] = {v0.x, v0.y, v0.z, v0.w, v1.x, v1.y, v1.z, v1.w};

    u32 hw[4];
    #pragma unroll
    for (int q = 0; q < 4; ++q)
        hw[q] = (u32)f2bf(vv[2 * q]) | ((u32)f2bf(vv[2 * q + 1]) << 16);
    uint4 hv = {hw[0], hw[1], hw[2], hw[3]};
    *(uint4*)(hi + (size_t)gid * 8) = hv;
}

// ---------------------------------------------------------------------------
// prep_all (2242 work + 128 fill = 2370 blocks, 256 thr)
// ---------------------------------------------------------------------------
__global__ __launch_bounds__(256)
void prep_all(const float* __restrict__ ideal, const float* __restrict__ W1,
              const float* __restrict__ We1, const float* __restrict__ W2,
              const float* __restrict__ b2, const float* __restrict__ be1,
              u16* __restrict__ xh, u16* __restrict__ w1h,
              u16* __restrict__ wabh, float* __restrict__ bab,
              float4* __restrict__ out4)
{
    const int bid = blockIdx.x;
    if (bid < 2048) {
        pack_body(ideal, xh, 1024, 4, bid * 256 + threadIdx.x);
    } else if (bid < 2176) {
        pack_body(W1, w1h, 1024, 4, (bid - 2048) * 256 + threadIdx.x);
    } else if (bid < 2240) {
        const int r0 = (bid - 2176) * 8;
        const int c  = threadIdx.x;
        float acc[8] = {};
        for (int k = 0; k < 256; ++k) {
            const float w2 = W2[k * 256 + c];
            #pragma unroll
            for (int j = 0; j < 8; ++j) {
                const int r = r0 + j;
                acc[j] += We1[(size_t)(r & 255) * 512 + ((r >> 8) << 8) + k] * w2;
            }
        }
        const int kc = c >> 6, kb = (c >> 3) & 7, e = c & 7;
        #pragma unroll
        for (int j = 0; j < 8; ++j) {
            const int r = r0 + j;
            wabh[(((((size_t)(r >> 6) << 2) + kc) << 3) + kb) * 512 + (size_t)(r & 63) * 8 + e]
                = f2bf(acc[j]);
        }
    } else if (bid < 2242) {
        const int r = (bid - 2240) * 256 + threadIdx.x;
        const int i = r & 255;
        const int koff = (r >> 8) << 8;
        float acc = (r < 256) ? be1[i] : 0.0f;
        for (int k = 0; k < 256; k += 4) {
            const float4 w = *(const float4*)(We1 + (size_t)i * 512 + koff + k);
            const float4 b = *(const float4*)(b2 + k);
            acc += w.x * b.x + w.y * b.y + w.z * b.z + w.w * b.w;
        }
        bab[r] = acc;
    } else {
        fill_shard(out4, 0, bid - 2242, threadIdx.x);
    }
}

// ---------------------------------------------------------------------------
// gemm12: row-local fused node pipeline. 512 blocks x 512 thr.
//   blocks [0,256):   16 rows each. 8 waves.
//     phase1: wave w -> h1 cols [32w,32w+32) (2 frags), K=1024, 16 t-steps;
//             frags direct from packed xh/w1h (no LDS, no barriers).
//             epilogue: relu+b1 -> H1 LDS (phase2 A-frag layout, 8KB).
//     one __syncthreads.
//     phase2: wave w -> AB cols [64w,64w+64) (4 frags), K=256, 4 t-steps;
//             A-frags from H1 LDS, W-frags direct from wabh (L2-hot).
//   blocks [256,512): fill shards 1,2 (512 thr x 16 float4 each).
// ---------------------------------------------------------------------------
__global__ __launch_bounds__(512)
void gemm12(const u16* __restrict__ xh, const u16* __restrict__ w1h,
            const u16* __restrict__ wabh, const float* __restrict__ b1,
            const float* __restrict__ bab, u16* __restrict__ ABout,
            float4* __restrict__ out4)
{
    const int b = blockIdx.x;
    if (b >= 256) {
        // fill shards 1+2: region float4 [1048576, 3145728)
        const int fb = b - 256;
        float4* op = out4 + 1048576 + (size_t)fb * 8192 + threadIdx.x;
        const float4 z = {0.f, 0.f, 0.f, 0.f};
        #pragma unroll 8
        for (int q = 0; q < 16; ++q)
            op[(size_t)q * 512] = z;
        return;
    }

    __shared__ u16 H1[4096];          // [kb32][row16][e8] = 8 KB
    const int tid  = threadIdx.x;
    const int wv   = tid >> 6;        // 0..7
    const int lane = tid & 63;
    const int kq   = lane >> 4;
    const int r16  = lane & 15;
    const int p    = b >> 2;          // 64-row source panel
    const int r0   = (b & 3) << 4;    // 16-row slice within panel

    // ---- phase 1: h1 cols [32w, 32w+32) ----
    const int pn1 = wv >> 1;                       // W1 64-col panel
    const u16* pa1 = xh + (((size_t)p * 16) << 12) + ((size_t)(r0 + r16) << 3);
    const u16* pw1 = w1h + (((size_t)pn1 * 16) << 12);

    f32x4 acc1[2];
    acc1[0] = (f32x4){0.f, 0.f, 0.f, 0.f};
    acc1[1] = (f32x4){0.f, 0.f, 0.f, 0.f};

    #pragma unroll 4
    for (int t = 0; t < 16; ++t) {
        #pragma unroll
        for (int s = 0; s < 2; ++s) {
            const int kb = (s << 2) + kq;
            const bf16x8 af = *(const bf16x8*)(pa1 + ((size_t)t << 12) + (kb << 9));
            #pragma unroll
            for (int n = 0; n < 2; ++n) {
                const int c0 = ((wv & 1) << 5) + (n << 4);     // col within panel
                const bf16x8 bf = *(const bf16x8*)
                    (pw1 + ((size_t)t << 12) + (kb << 9) + ((size_t)(c0 + r16) << 3));
                acc1[n] = __builtin_amdgcn_mfma_f32_16x16x32_bf16(af, bf, acc1[n], 0, 0, 0);
            }
        }
    }

    // epilogue -> H1 (phase2 A-frag layout). D: col=r16(out col), row=kq*4+j.
    #pragma unroll
    for (int n = 0; n < 2; ++n) {
        const int col = (wv << 5) + (n << 4) + r16;    // h1 col 0..255
        const float bv = b1[col];
        const int kb2 = col >> 3;                      // 0..31
        #pragma unroll
        for (int j = 0; j < 4; ++j) {
            const float v = fmaxf(acc1[n][j] + bv, 0.0f);
            H1[(((kb2 << 4) + (kq << 2) + j) << 3) + (col & 7)] = f2bf(v);
        }
    }
    __syncthreads();

    // ---- phase 2: AB cols [64w, 64w+64) ----
    const u16* pw2 = wabh + (((size_t)wv * 4) << 12);
    f32x4 acc2[4];
    #pragma unroll
    for (int n = 0; n < 4; ++n) acc2[n] = (f32x4){0.f, 0.f, 0.f, 0.f};

    #pragma unroll
    for (int t = 0; t < 4; ++t) {
        #pragma unroll
        for (int s = 0; s < 2; ++s) {
            const int kb = (s << 2) + kq;
            const int kb32 = (t << 3) + kb;
            const bf16x8 af = *(const bf16x8*)&H1[((kb32 << 4) + r16) << 3];
            #pragma unroll
            for (int n = 0; n < 4; ++n) {
                const bf16x8 bf = *(const bf16x8*)
                    (pw2 + ((size_t)t << 12) + (kb << 9) + ((size_t)((n << 4) + r16) << 3));
                acc2[n] = __builtin_amdgcn_mfma_f32_16x16x32_bf16(af, bf, acc2[n], 0, 0, 0);
            }
        }
    }

    #pragma unroll
    for (int n = 0; n < 4; ++n) {
        const int col = (wv << 6) + (n << 4) + r16;    // 0..511
        const float bv = bab[col];
        #pragma unroll
        for (int j = 0; j < 4; ++j) {
            const int row = (b << 4) + (kq << 2) + j;
            ABout[(size_t)row * 512 + col] = f2bf(acc2[n][j] + bv);
        }
    }
}

// ---------------------------------------------------------------------------
// edge_z (2048 edge + 128 fill = 2176 blocks, 256 thr)
// ---------------------------------------------------------------------------
__global__ __launch_bounds__(256)
void edge_z(const u16* __restrict__ AB, const int* __restrict__ idx,
            const float* __restrict__ We2, const float* __restrict__ be2p,
            float* __restrict__ vbuf, float* __restrict__ part,
            float4* __restrict__ out4)
{
    const int bid = blockIdx.x;
    const int tid = threadIdx.x;

    if (bid >= 2048) {
        fill_shard(out4, 3, bid - 2048, tid);
        return;
    }

    __shared__ float sm[256];
    const int cb   = bid;                        // 0..2047
    const int lane = tid & 63;
    const int sub  = lane >> 5;
    const int l5   = lane & 31;
    const int wid  = (cb * 256 + tid) >> 6;      // 0..8191
    const float be2 = be2p[0];

    float w2v[8];
    #pragma unroll
    for (int q = 0; q < 2; ++q) {
        const float4 w = ((const float4*)We2)[l5 * 2 + q];
        w2v[q * 4 + 0] = w.x; w2v[q * 4 + 1] = w.y;
        w2v[q * 4 + 2] = w.z; w2v[q * 4 + 3] = w.w;
    }

    float zloc = 0.0f;
    #pragma unroll
    for (int it = 0; it < 8; ++it) {
        const int e = (wid << 1) + sub + (it << 14);    // covers [0, 131072)
        const int src = idx[2 * e];
        const int dst = idx[2 * e + 1];
        const uint4 av = *(const uint4*)(AB + ((size_t)src << 9) + (l5 << 3));
        const uint4 bv = *(const uint4*)(AB + ((size_t)dst << 9) + 256 + (l5 << 3));
        const u32 aw[4] = {av.x, av.y, av.z, av.w};
        const u32 bw[4] = {bv.x, bv.y, bv.z, bv.w};
        float p = 0.0f;
        #pragma unroll
        for (int q = 0; q < 4; ++q) {
            p += fmaxf(bflo(aw[q]) + bflo(bw[q]), 0.0f) * w2v[2 * q];
            p += fmaxf(bfhi(aw[q]) + bfhi(bw[q]), 0.0f) * w2v[2 * q + 1];
        }
        #pragma unroll
        for (int m = 16; m > 0; m >>= 1)
            p += __shfl_xor(p, m, 64);   // xor<32: stays within the half-wave
        const float v = expf(p + be2);
        if (l5 == 0) {
            vbuf[e] = v;
            zloc += v;                   // one lane per edge contributes
        }
    }
    sm[tid] = zloc;
    __syncthreads();
    for (int st = 128; st > 0; st >>= 1) {
        if (tid < st) sm[tid] += sm[tid + st];
        __syncthreads();
    }
    if (tid == 0) part[cb] = sm[0];
}

// fused: finalize Z over part[2048] (redundant per block) + scatter probs
__global__ __launch_bounds__(256)
void scatter_probs(const float* __restrict__ vbuf, const int* __restrict__ idx,
                   const float* __restrict__ part, float* __restrict__ out, int n)
{
    __shared__ float sm[256];
    float a = part[threadIdx.x];
    #pragma unroll
    for (int k = 1; k < 8; ++k)
        a += part[threadIdx.x + k * 256];
    sm[threadIdx.x] = a;
    __syncthreads();
    for (int st = 128; st > 0; st >>= 1) {
        if (threadIdx.x < st) sm[threadIdx.x] += sm[threadIdx.x + st];
        __syncthreads();
    }
    const float Z = sm[0];
    const int e = blockIdx.x * 256 + threadIdx.x;
    if (e < n)
        out[(size_t)idx[2 * e] * N_NODES + idx[2 * e + 1]] = vbuf[e] / Z;
}

// ---------------------------------------------------------------------------
extern "C" void kernel_launch(void* const* d_in, const int* in_sizes, int n_in,
                              void* d_out, int out_size, void* d_ws, size_t ws_size,
                              hipStream_t stream)
{
    const float* ideal = (const float*)d_in[0];   // 4096 x 1024
    const int*   idx   = (const int*)d_in[1];     // E x 2
    const float* W1    = (const float*)d_in[2];   // 256 x 1024
    const float* b1    = (const float*)d_in[3];   // 256
    const float* W2    = (const float*)d_in[4];   // 256 x 256
    const float* b2    = (const float*)d_in[5];   // 256
    const float* We1   = (const float*)d_in[6];   // 256 x 512
    const float* be1   = (const float*)d_in[7];   // 256
    const float* We2   = (const float*)d_in[8];   // 256
    const float* be2   = (const float*)d_in[9];   // 1
    float* out = (float*)d_out;

    char* Wb = (char*)d_ws;
    u16*   xh   = (u16*)(Wb);                          // 8 MB packed x
    u16*   w1h  = (u16*)(Wb + (8u << 20));             // 512 KB packed W1
    u16*   wabh = (u16*)(Wb + (8u << 20) + (512u << 10)); // 256 KB packed Wab
    float* bab  = (float*)(Wb + (9u << 20));           // 2 KB
    u16*   ABbf = (u16*)(Wb + (10u << 20));            // 4 MB bf16 AB row-major
    float* vbuf = (float*)(Wb + (15u << 20));          // 512 KB exp(scores)
    float* part = vbuf + E_EDGES;                      // 2048 partial Z

    // pack + fold (+ fill shard 0)
    prep_all<<<2370, 256, 0, stream>>>(ideal, W1, We1, W2, b2, be1,
                                       xh, w1h, wabh, bab, (float4*)out);

    // fused node pipeline: AB = relu(x@W1.T+b1)@Wab.T + bab (+ fill shards 1,2)
    gemm12<<<512, 512, 0, stream>>>(xh, w1h, wabh, b1, bab, ABbf, (float4*)out);

    // edge scores + partial Z (+ fill shard 3)
    edge_z<<<2176, 256, 0, stream>>>(ABbf, idx, We2, be2, vbuf, part, (float4*)out);
    // Z finalize (redundant per block) + scatter
    scatter_probs<<<512, 256, 0, stream>>>(vbuf, idx, part, out, E_EDGES);
}

// Round 20
// 65.953 us; speedup vs baseline: 1.0787x; 1.0109x over previous
//
#include <hip/hip_runtime.h>
#include <hip/hip_bf16.h>

// TwinPolicy, pure-bf16 MFMA pipeline (4 launches):
//   prep_all (322 blocks): pack W1 -> w1h, fold Wab=(We1@W2) -> wabh, bab
//                          (+ fill shard 0)
//   gemm12: row-local fused node pipeline. Block = 16 rows, 8 waves:
//     prologue: read own 16 rows of x COALESCED, f2bf once -> Xp LDS (34KB,
//               +16B/kb pad). One barrier.  (kills the 16MB xh round-trip;
//               NOT the R12 trap: cvt once per element, prologue not K-loop)
//     phase1 h1=relu(x@W1.T+b1): A-frags from Xp, W1 frags direct global.
//     One barrier. phase2 AB=h1@Wab.T+bab from H1 LDS + L2-hot wabh.
//     (+ 256 tail blocks fill shards 1,2)
//   edge_z: v[e]=exp(s[e]) + block partial Z (+ fill shard 3)
//   scatter_probs: redundant Z-reduce + out[src,dst] = v/Z
// f2bf points and K-order identical to R19 -> bit-identical output.

typedef unsigned short u16;
typedef unsigned int   u32;
typedef __attribute__((ext_vector_type(8))) short bf16x8;
typedef __attribute__((ext_vector_type(4))) float f32x4;

#define N_NODES 4096
#define E_EDGES 131072
#define AS1 __attribute__((address_space(1)))
#define AS3 __attribute__((address_space(3)))

__device__ __forceinline__ u16 f2bf(float f) {
    u32 u = __float_as_uint(f);
    return (u16)((u + 0x7FFFu + ((u >> 16) & 1u)) >> 16);
}
__device__ __forceinline__ float bflo(u32 w) { return __uint_as_float(w << 16); }
__device__ __forceinline__ float bfhi(u32 w) { return __uint_as_float(w & 0xffff0000u); }

// fill shard s (of 4), block fb (of 128), 256-thr: 128*256*32 float4 = 16.77MB
__device__ __forceinline__ void fill_shard(float4* __restrict__ out4,
                                           int shard, int fb, int tid)
{
    float4* op = out4 + (size_t)shard * 1048576 + (size_t)fb * 8192 + tid;
    const float4 z = {0.f, 0.f, 0.f, 0.f};
    #pragma unroll 8
    for (int q = 0; q < 32; ++q)
        op[(size_t)q * 256] = z;
}

// ---------------------------------------------------------------------------
// Pack f32 [M][K] -> bf16, MFMA-ready layout:
// elem(row,k) -> ((((row>>6)*KC + (k>>6))*8 + ((k>>3)&7))*64 + (row&63))*8 + (k&7)
// ---------------------------------------------------------------------------
__device__ __forceinline__ void pack_body(const float* __restrict__ in,
                                          u16* __restrict__ hi, int K, int kcs, int gid)
{
    const int r   = gid & 63;
    const int kb  = (gid >> 6) & 7;
    const int pkc = gid >> 9;
    const int kc  = pkc & ((1 << kcs) - 1);
    const int p   = pkc >> kcs;
    const size_t row = ((size_t)p << 6) | r;
    const int k0 = (kc << 6) | (kb << 3);

    const float* src = in + row * (size_t)K + k0;
    const float4 v0 = *(const float4*)src;
    const float4 v1 = *(const float4*)(src + 4);
    const float vv[8] = {v0.x, v0.y, v0.z, v0.w, v1.x, v1.y, v1.z, v1.w};

    u32 hw[4];
    #pragma unroll
    for (int q = 0; q < 4; ++q)
        hw[q] = (u32)f2bf(vv[2 * q]) | ((u32)f2bf(vv[2 * q + 1]) << 16);
    uint4 hv = {hw[0], hw[1], hw[2], hw[3]};
    *(uint4*)(hi + (size_t)gid * 8) = hv;
}

// ---------------------------------------------------------------------------
// prep_all (194 work + 128 fill = 322 blocks, 256 thr):
//   [0,128):   pack W1 (256x1024) -> w1h
//   [128,192): Wab[r][c] = (r<256 ? We1a@W2 : We1b@W2), packed bf16 W-layout
//   [192,194): bab[r] = (r<256 ? be1[r] : 0) + dot(We1 row-part, b2)
//   [194,322): fill shard 0
// ---------------------------------------------------------------------------
__global__ __launch_bounds__(256)
void prep_all(const float* __restrict__ W1, const float* __restrict__ We1,
              const float* __restrict__ W2, const float* __restrict__ b2,
              const float* __restrict__ be1,
              u16* __restrict__ w1h, u16* __restrict__ wabh,
              float* __restrict__ bab, float4* __restrict__ out4)
{
    const int bid = blockIdx.x;
    if (bid < 128) {
        pack_body(W1, w1h, 1024, 4, bid * 256 + threadIdx.x);
    } else if (bid < 192) {
        const int r0 = (bid - 128) * 8;
        const int c  = threadIdx.x;
        float acc[8] = {};
        for (int k = 0; k < 256; ++k) {
            const float w2 = W2[k * 256 + c];
            #pragma unroll
            for (int j = 0; j < 8; ++j) {
                const int r = r0 + j;
                acc[j] += We1[(size_t)(r & 255) * 512 + ((r >> 8) << 8) + k] * w2;
            }
        }
        const int kc = c >> 6, kb = (c >> 3) & 7, e = c & 7;
        #pragma unroll
        for (int j = 0; j < 8; ++j) {
            const int r = r0 + j;
            wabh[(((((size_t)(r >> 6) << 2) + kc) << 3) + kb) * 512 + (size_t)(r & 63) * 8 + e]
                = f2bf(acc[j]);
        }
    } else if (bid < 194) {
        const int r = (bid - 192) * 256 + threadIdx.x;
        const int i = r & 255;
        const int koff = (r >> 8) << 8;
        float acc = (r < 256) ? be1[i] : 0.0f;
        for (int k = 0; k < 256; k += 4) {
            const float4 w = *(const float4*)(We1 + (size_t)i * 512 + koff + k);
            const float4 b = *(const float4*)(b2 + k);
            acc += w.x * b.x + w.y * b.y + w.z * b.z + w.w * b.w;
        }
        bab[r] = acc;
    } else {
        fill_shard(out4, 0, bid - 194, threadIdx.x);
    }
}

// ---------------------------------------------------------------------------
// gemm12: row-local fused node pipeline with in-block x pack.
// 512 blocks x 512 thr.
//   blocks [0,256): 16 rows each, 8 waves.
//     prologue: 2048 frag-slots; gid=(q<<9)+tid, kb=gid&127, row=gid>>7 ->
//       coalesced 32B f32 reads along k; f2bf; Xp[kb*136 + row*8] (pad 16B/kb).
//     phase1: wave w -> h1 cols [32w,32w+32), K=1024, 16 t-steps;
//       A-frags from Xp LDS, W1 frags direct global (packed w1h).
//       epilogue relu+b1 -> H1 LDS (phase2 A-frag layout, 8KB).
//     phase2: wave w -> AB cols [64w,64w+64), K=256; Wab frags L2-hot global.
//   blocks [256,512): fill shards 1,2 (512 thr x 16 float4 each).
// LDS 42KB -> 3 blocks/CU.
// ---------------------------------------------------------------------------
__global__ __launch_bounds__(512)
void gemm12(const float* __restrict__ X, const u16* __restrict__ w1h,
            const u16* __restrict__ wabh, const float* __restrict__ b1,
            const float* __restrict__ bab, u16* __restrict__ ABout,
            float4* __restrict__ out4)
{
    const int b = blockIdx.x;
    if (b >= 256) {
        // fill shards 1+2: region float4 [1048576, 3145728)
        const int fb = b - 256;
        float4* op = out4 + 1048576 + (size_t)fb * 8192 + threadIdx.x;
        const float4 z = {0.f, 0.f, 0.f, 0.f};
        #pragma unroll 8
        for (int q = 0; q < 16; ++q)
            op[(size_t)q * 512] = z;
        return;
    }

    __shared__ u16 Xp[17408];         // 128 kb-groups * 136 u16 (pad) = 34 KB
    __shared__ u16 H1[4096];          // [kb32][row16][e8] = 8 KB
    const int tid  = threadIdx.x;
    const int wv   = tid >> 6;        // 0..7
    const int lane = tid & 63;
    const int kq   = lane >> 4;
    const int r16  = lane & 15;
    const int R0   = b << 4;          // first of this block's 16 rows

    // ---- prologue: pack own 16 rows of x into Xp (coalesced reads) ----
    #pragma unroll
    for (int q = 0; q < 4; ++q) {
        const int gid = (q << 9) + tid;        // 0..2047
        const int kb  = gid & 127;             // k-slice (8 elems)
        const int row = gid >> 7;              // 0..15
        const float* src = X + (size_t)(R0 + row) * 1024 + (kb << 3);
        const float4 v0 = *(const float4*)src;
        const float4 v1 = *(const float4*)(src + 4);
        const float vv[8] = {v0.x, v0.y, v0.z, v0.w, v1.x, v1.y, v1.z, v1.w};
        u32 hw[4];
        #pragma unroll
        for (int e = 0; e < 4; ++e)
            hw[e] = (u32)f2bf(vv[2 * e]) | ((u32)f2bf(vv[2 * e + 1]) << 16);
        uint4 hv = {hw[0], hw[1], hw[2], hw[3]};
        *(uint4*)&Xp[kb * 136 + (row << 3)] = hv;
    }
    __syncthreads();

    // ---- phase 1: h1 cols [32w, 32w+32) ----
    const int pn1 = wv >> 1;                       // W1 64-col panel
    const u16* pw1 = w1h + (((size_t)pn1 * 16) << 12);

    f32x4 acc1[2];
    acc1[0] = (f32x4){0.f, 0.f, 0.f, 0.f};
    acc1[1] = (f32x4){0.f, 0.f, 0.f, 0.f};

    #pragma unroll 4
    for (int t = 0; t < 16; ++t) {
        #pragma unroll
        for (int s = 0; s < 2; ++s) {
            const int kb  = (s << 2) + kq;
            const int kbg = (t << 3) + kb;         // global k-slice 0..127
            const bf16x8 af = *(const bf16x8*)&Xp[kbg * 136 + (r16 << 3)];
            #pragma unroll
            for (int n = 0; n < 2; ++n) {
                const int c0 = ((wv & 1) << 5) + (n << 4);     // col within panel
                const bf16x8 bf = *(const bf16x8*)
                    (pw1 + ((size_t)t << 12) + (kb << 9) + ((size_t)(c0 + r16) << 3));
                acc1[n] = __builtin_amdgcn_mfma_f32_16x16x32_bf16(af, bf, acc1[n], 0, 0, 0);
            }
        }
    }

    // epilogue -> H1 (phase2 A-frag layout). D: col=r16(out col), row=kq*4+j.
    #pragma unroll
    for (int n = 0; n < 2; ++n) {
        const int col = (wv << 5) + (n << 4) + r16;    // h1 col 0..255
        const float bv = b1[col];
        const int kb2 = col >> 3;                      // 0..31
        #pragma unroll
        for (int j = 0; j < 4; ++j) {
            const float v = fmaxf(acc1[n][j] + bv, 0.0f);
            H1[(((kb2 << 4) + (kq << 2) + j) << 3) + (col & 7)] = f2bf(v);
        }
    }
    __syncthreads();

    // ---- phase 2: AB cols [64w, 64w+64) ----
    const u16* pw2 = wabh + (((size_t)wv * 4) << 12);
    f32x4 acc2[4];
    #pragma unroll
    for (int n = 0; n < 4; ++n) acc2[n] = (f32x4){0.f, 0.f, 0.f, 0.f};

    #pragma unroll
    for (int t = 0; t < 4; ++t) {
        #pragma unroll
        for (int s = 0; s < 2; ++s) {
            const int kb = (s << 2) + kq;
            const int kb32 = (t << 3) + kb;
            const bf16x8 af = *(const bf16x8*)&H1[((kb32 << 4) + r16) << 3];
            #pragma unroll
            for (int n = 0; n < 4; ++n) {
                const bf16x8 bf = *(const bf16x8*)
                    (pw2 + ((size_t)t << 12) + (kb << 9) + ((size_t)((n << 4) + r16) << 3));
                acc2[n] = __builtin_amdgcn_mfma_f32_16x16x32_bf16(af, bf, acc2[n], 0, 0, 0);
            }
        }
    }

    #pragma unroll
    for (int n = 0; n < 4; ++n) {
        const int col = (wv << 6) + (n << 4) + r16;    // 0..511
        const float bv = bab[col];
        #pragma unroll
        for (int j = 0; j < 4; ++j) {
            const int row = R0 + (kq << 2) + j;
            ABout[(size_t)row * 512 + col] = f2bf(acc2[n][j] + bv);
        }
    }
}

// ---------------------------------------------------------------------------
// edge_z (2048 edge + 128 fill = 2176 blocks, 256 thr)
// ---------------------------------------------------------------------------
__global__ __launch_bounds__(256)
void edge_z(const u16* __restrict__ AB, const int* __restrict__ idx,
            const float* __restrict__ We2, const float* __restrict__ be2p,
            float* __restrict__ vbuf, float* __restrict__ part,
            float4* __restrict__ out4)
{
    const int bid = blockIdx.x;
    const int tid = threadIdx.x;

    if (bid >= 2048) {
        fill_shard(out4, 3, bid - 2048, tid);
        return;
    }

    __shared__ float sm[256];
    const int cb   = bid;                        // 0..2047
    const int lane = tid & 63;
    const int sub  = lane >> 5;
    const int l5   = lane & 31;
    const int wid  = (cb * 256 + tid) >> 6;      // 0..8191
    const float be2 = be2p[0];

    float w2v[8];
    #pragma unroll
    for (int q = 0; q < 2; ++q) {
        const float4 w = ((const float4*)We2)[l5 * 2 + q];
        w2v[q * 4 + 0] = w.x; w2v[q * 4 + 1] = w.y;
        w2v[q * 4 + 2] = w.z; w2v[q * 4 + 3] = w.w;
    }

    float zloc = 0.0f;
    #pragma unroll
    for (int it = 0; it < 8; ++it) {
        const int e = (wid << 1) + sub + (it << 14);    // covers [0, 131072)
        const int src = idx[2 * e];
        const int dst = idx[2 * e + 1];
        const uint4 av = *(const uint4*)(AB + ((size_t)src << 9) + (l5 << 3));
        const uint4 bv = *(const uint4*)(AB + ((size_t)dst << 9) + 256 + (l5 << 3));
        const u32 aw[4] = {av.x, av.y, av.z, av.w};
        const u32 bw[4] = {bv.x, bv.y, bv.z, bv.w};
        float p = 0.0f;
        #pragma unroll
        for (int q = 0; q < 4; ++q) {
            p += fmaxf(bflo(aw[q]) + bflo(bw[q]), 0.0f) * w2v[2 * q];
            p += fmaxf(bfhi(aw[q]) + bfhi(bw[q]), 0.0f) * w2v[2 * q + 1];
        }
        #pragma unroll
        for (int m = 16; m > 0; m >>= 1)
            p += __shfl_xor(p, m, 64);   // xor<32: stays within the half-wave
        const float v = expf(p + be2);
        if (l5 == 0) {
            vbuf[e] = v;
            zloc += v;                   // one lane per edge contributes
        }
    }
    sm[tid] = zloc;
    __syncthreads();
    for (int st = 128; st > 0; st >>= 1) {
        if (tid < st) sm[tid] += sm[tid + st];
        __syncthreads();
    }
    if (tid == 0) part[cb] = sm[0];
}

// fused: finalize Z over part[2048] (redundant per block) + scatter probs
__global__ __launch_bounds__(256)
void scatter_probs(const float* __restrict__ vbuf, const int* __restrict__ idx,
                   const float* __restrict__ part, float* __restrict__ out, int n)
{
    __shared__ float sm[256];
    float a = part[threadIdx.x];
    #pragma unroll
    for (int k = 1; k < 8; ++k)
        a += part[threadIdx.x + k * 256];
    sm[threadIdx.x] = a;
    __syncthreads();
    for (int st = 128; st > 0; st >>= 1) {
        if (threadIdx.x < st) sm[threadIdx.x] += sm[threadIdx.x + st];
        __syncthreads();
    }
    const float Z = sm[0];
    const int e = blockIdx.x * 256 + threadIdx.x;
    if (e < n)
        out[(size_t)idx[2 * e] * N_NODES + idx[2 * e + 1]] = vbuf[e] / Z;
}

// ---------------------------------------------------------------------------
extern "C" void kernel_launch(void* const* d_in, const int* in_sizes, int n_in,
                              void* d_out, int out_size, void* d_ws, size_t ws_size,
                              hipStream_t stream)
{
    const float* ideal = (const float*)d_in[0];   // 4096 x 1024
    const int*   idx   = (const int*)d_in[1];     // E x 2
    const float* W1    = (const float*)d_in[2];   // 256 x 1024
    const float* b1    = (const float*)d_in[3];   // 256
    const float* W2    = (const float*)d_in[4];   // 256 x 256
    const float* b2    = (const float*)d_in[5];   // 256
    const float* We1   = (const float*)d_in[6];   // 256 x 512
    const float* be1   = (const float*)d_in[7];   // 256
    const float* We2   = (const float*)d_in[8];   // 256
    const float* be2   = (const float*)d_in[9];   // 1
    float* out = (float*)d_out;

    char* Wb = (char*)d_ws;
    u16*   w1h  = (u16*)(Wb);                          // 512 KB packed W1
    u16*   wabh = (u16*)(Wb + (512u << 10));           // 256 KB packed Wab
    float* bab  = (float*)(Wb + (768u << 10));         // 2 KB
    u16*   ABbf = (u16*)(Wb + (1u << 20));             // 4 MB bf16 AB row-major
    float* vbuf = (float*)(Wb + (6u << 20));           // 512 KB exp(scores)
    float* part = vbuf + E_EDGES;                      // 2048 partial Z

    // weight prep (+ fill shard 0)
    prep_all<<<322, 256, 0, stream>>>(W1, We1, W2, b2, be1,
                                      w1h, wabh, bab, (float4*)out);

    // fused node pipeline, x packed in-block (+ fill shards 1,2)
    gemm12<<<512, 512, 0, stream>>>(ideal, w1h, wabh, b1, bab, ABbf, (float4*)out);

    // edge scores + partial Z (+ fill shard 3)
    edge_z<<<2176, 256, 0, stream>>>(ABbf, idx, We2, be2, vbuf, part, (float4*)out);
    // Z finalize (redundant per block) + scatter
    scatter_probs<<<512, 256, 0, stream>>>(vbuf, idx, part, out, E_EDGES);
}